// Round 9
// baseline (36651.932 us; speedup 1.0000x reference)
//
#include <hip/hip_runtime.h>

typedef unsigned long long u64;
typedef unsigned int u32;
typedef unsigned short u16;
typedef _Float16 f16;
typedef _Float16 h2 __attribute__((ext_vector_type(2)));

#define BB 16
#define TT 1500
#define NG3 1536
#define GM (BB * TT)   /* 24000 */
#define GK 512
#define LNEPS 1e-5f
#define FL 64          /* flag line stride in u32 (256B) */
#define NWGL 48        /* WGs per layer (32 cols each) */
#define GW0 768        /* u64 (f16-pair) per batch row, layer 0 */
#define GW1 1024       /* + x_n section, layer 1 */
#define HSLOT (BB * 256) /* u64 per Hb0 ring slot */

// ---------------- helpers ----------------
__device__ __forceinline__ float sigmoidf_(float x) { return 1.f / (1.f + __expf(-x)); }
__device__ __forceinline__ float tanhf_(float x) {
  x = fminf(15.f, fmaxf(-15.f, x));
  float e = __expf(2.f * x);
  return (e - 1.f) / (e + 1.f);
}
__device__ __forceinline__ float red16_(float v) {
  v += __shfl_xor(v, 1, 64); v += __shfl_xor(v, 2, 64);
  v += __shfl_xor(v, 4, 64); v += __shfl_xor(v, 8, 64);
  return v;
}
__device__ __forceinline__ float red64_(float v) {
  v += __shfl_xor(v, 1, 64);  v += __shfl_xor(v, 2, 64);
  v += __shfl_xor(v, 4, 64);  v += __shfl_xor(v, 8, 64);
  v += __shfl_xor(v, 16, 64); v += __shfl_xor(v, 32, 64);
  return v;
}
__device__ __forceinline__ u64 ldA(const u64* p) {
  return __hip_atomic_load(p, __ATOMIC_RELAXED, __HIP_MEMORY_SCOPE_AGENT);
}
__device__ __forceinline__ void stA8(u64* p, u64 v) {
  __hip_atomic_store(p, v, __ATOMIC_RELAXED, __HIP_MEMORY_SCOPE_AGENT);
}
__device__ __forceinline__ u32 ldA32(const u32* p) {
  return __hip_atomic_load(p, __ATOMIC_RELAXED, __HIP_MEMORY_SCOPE_AGENT);
}
__device__ __forceinline__ void stA32(u32* p, u32 v) {
  __hip_atomic_store(p, v, __ATOMIC_RELAXED, __HIP_MEMORY_SCOPE_AGENT);
}
__device__ __forceinline__ u32 pkh2(float a, float b) {
  u16 sa = __builtin_bit_cast(u16, (f16)a);
  u16 sb = __builtin_bit_cast(u16, (f16)b);
  return (u32)sa | ((u32)sb << 16);
}
__device__ __forceinline__ u64 pk2(u32 tag, float a, float b) {
  return ((u64)tag << 32) | (u64)pkh2(a, b);
}
__device__ __forceinline__ float f16lo(u32 p) {
  u16 s = (u16)p; return (float)__builtin_bit_cast(f16, s);
}
__device__ __forceinline__ float f16hi(u32 p) {
  u16 s = (u16)(p >> 16); return (float)__builtin_bit_cast(f16, s);
}
__device__ __forceinline__ h2 bch2(u32 u) { return __builtin_bit_cast(h2, u); }
__device__ __forceinline__ float dot2f(h2 a, h2 b, float c) {
#if __has_builtin(__builtin_amdgcn_fdot2)
  return __builtin_amdgcn_fdot2(a, b, c, false);
#else
  return fmaf((float)a.y, (float)b.y, fmaf((float)a.x, (float)b.x, c));
#endif
}
// swizzled 16B-chunk index within a 64-chunk (1KB) h row: exactly 2-way banks
__device__ __forceinline__ int physp(int c) { return c ^ ((c >> 2) & 7); }

// ---------------- big GEMM: C[M,N] = A[M,K] @ W[N,K]^T (fp32) ----------------
__global__ __launch_bounds__(256) void gemm_nt(const float* __restrict__ A,
                                               const float* __restrict__ W,
                                               float* __restrict__ C) {
  __shared__ __align__(16) float As[32][68];
  __shared__ __align__(16) float Ws[32][68];
  const int m0 = blockIdx.x * 64;
  const int n0 = blockIdx.y * 64;
  const int tid = threadIdx.x;
  const int tm = tid & 15, tn = tid >> 4;
  float acc[4][4] = {};
  for (int k0 = 0; k0 < GK; k0 += 32) {
#pragma unroll
    for (int u = 0; u < 2; ++u) {
      int idx = tid + u * 256;
      int r = idx >> 3;
      int kq = (idx & 7) * 4;
      float4 a = *reinterpret_cast<const float4*>(&A[(size_t)(m0 + r) * GK + k0 + kq]);
      As[kq + 0][r] = a.x; As[kq + 1][r] = a.y; As[kq + 2][r] = a.z; As[kq + 3][r] = a.w;
      float4 w = *reinterpret_cast<const float4*>(&W[(size_t)(n0 + r) * GK + k0 + kq]);
      Ws[kq + 0][r] = w.x; Ws[kq + 1][r] = w.y; Ws[kq + 2][r] = w.z; Ws[kq + 3][r] = w.w;
    }
    __syncthreads();
#pragma unroll
    for (int kk = 0; kk < 32; ++kk) {
      float a[4], w[4];
      *reinterpret_cast<float4*>(a) = *reinterpret_cast<const float4*>(&As[kk][tm * 4]);
      *reinterpret_cast<float4*>(w) = *reinterpret_cast<const float4*>(&Ws[kk][tn * 4]);
#pragma unroll
      for (int i = 0; i < 4; ++i)
#pragma unroll
        for (int q = 0; q < 4; ++q)
          acc[i][q] = fmaf(a[i], w[q], acc[i][q]);
    }
    __syncthreads();
  }
#pragma unroll
  for (int i = 0; i < 4; ++i) {
    float4 v = make_float4(acc[i][0], acc[i][1], acc[i][2], acc[i][3]);
    *reinterpret_cast<float4*>(&C[(size_t)(m0 + tm * 4 + i) * NG3 + n0 + tn * 4]) = v;
  }
}

// ---------------- fused 2-layer GRU scan: 1-hop, f16 dot2, wave-owns-batch ----
// WG 0..47  : layer 0, cols wgl*32..+32. WG 48..95: layer 1 (dual matvec).
// Gates: G0 u64[2][16][768], G1 u64[2][16][1024] — (tag | f16 col-pair).
// Hb0 u64[4][16][256]: tagged f16-pair h0 ring L0->L1; prog: L1 consumption.
__global__ __launch_bounds__(256, 1) void gru_fused(
    const float* __restrict__ Wh0, const float* __restrict__ Wi1,
    const float* __restrict__ Wh1, const float* __restrict__ X0,
    const float* __restrict__ lnw, const float* __restrict__ lnb,
    float* __restrict__ out, u64* __restrict__ G0, u64* __restrict__ G1,
    u64* __restrict__ Hb0, u32* __restrict__ prog) {
  __shared__ __align__(16) u16 shA[BB][512];  // this layer's h (f16, swizzled chunks)
  __shared__ __align__(16) u16 shB[BB][512];  // L1: h0(t)

  const int tid = threadIdx.x, wg = blockIdx.x;
  const int lane = tid & 63, wave = tid >> 6;
  const int ks = lane & 15, cq = lane >> 4;
  const bool L1 = wg >= NWGL;
  const int wgl = L1 ? wg - NWGL : wg;
  const int pairIdx = wgl * 16 + wave * 4 + cq;  // global col-pair 0..767
  const int col0 = pairIdx * 2;
  const int rr = tid >> 4, q16 = tid & 15;       // h0-copy assignment

  // ---- persistent weights: f16 pairs (k = ks*32 + 2i, i=0..15) ----
  u32 whp[2][16], wip[2][16];
#pragma unroll
  for (int c = 0; c < 2; ++c) {
    const float* Wp = (L1 ? Wh1 : Wh0) + (size_t)(col0 + c) * 512 + ks * 32;
#pragma unroll
    for (int i = 0; i < 16; ++i) whp[c][i] = pkh2(Wp[2 * i], Wp[2 * i + 1]);
    if (L1) {
      const float* Wq = Wi1 + (size_t)(col0 + c) * 512 + ks * 32;
#pragma unroll
      for (int i = 0; i < 16; ++i) wip[c][i] = pkh2(Wq[2 * i], Wq[2 * i + 1]);
    } else {
#pragma unroll
      for (int i = 0; i < 16; ++i) wip[c][i] = 0;
    }
  }
  // ---- persistent LN params for this lane's 8 phase-2 cols ----
  const float* lnwL = lnw + (L1 ? NG3 : 0);
  const float* lnbL = lnb + (L1 ? NG3 : 0);
  float lw[24], lb[24];
#pragma unroll
  for (int g = 0; g < 3; ++g)
#pragma unroll
    for (int e = 0; e < 8; ++e) {
      lw[g * 8 + e] = lnwL[g * 512 + lane * 8 + e];
      lb[g * 8 + e] = lnbL[g * 512 + lane * 8 + e];
    }

  for (int idx = tid; idx < BB * 512; idx += 256) {
    (&shA[0][0])[idx] = 0; (&shB[0][0])[idx] = 0;
  }
  __syncthreads();

  u64* Gb = L1 ? G1 : G0;
  const int GW = L1 ? GW1 : GW0;

  for (int t = 0; t < TT; ++t) {
    const u32 want = (u32)(t + 1);

    if (L1) {
      // ---- poll + copy h0(t) ring slot -> shB ----
      const u64* src = Hb0 + (size_t)(t & 3) * HSLOT + (size_t)rr * 256 + q16 * 16;
      u32 pl[16];
#pragma unroll
      for (int half = 0; half < 2; ++half) {
        for (;;) {
          u32 bad = 0;
          u64 w[8];
#pragma unroll
          for (int i = 0; i < 8; ++i) {
            w[i] = ldA(src + half * 8 + i);
            bad |= (u32)(w[i] >> 32) ^ want;
          }
          if (!bad) {
#pragma unroll
            for (int i = 0; i < 8; ++i) pl[half * 8 + i] = (u32)w[i];
            break;
          }
          __builtin_amdgcn_s_sleep(1);
        }
      }
#pragma unroll
      for (int w = 0; w < 4; ++w) {
        int idx = physp(q16 * 4 + w) * 8;
        *reinterpret_cast<uint4*>(&shB[rr][idx]) =
            make_uint4(pl[4 * w], pl[4 * w + 1], pl[4 * w + 2], pl[4 * w + 3]);
      }
      __syncthreads();
      if (tid == 0) stA32(&prog[(size_t)wgl * FL], want);
    }

    // ---- matvec(s): lane=(ks,cq), dot2 over f16 LDS h ----
    float gA0 = 0.f, gA1 = 0.f, gB0 = 0.f, gB1 = 0.f;
#pragma unroll 4
    for (int b = 0; b < 16; ++b) {
      float p0 = 0.f, p1 = 0.f, q0 = 0.f, q1 = 0.f;
#pragma unroll
      for (int j = 0; j < 4; ++j) {
        const int idx = ((ks * 4 + j) ^ (ks & 7)) * 8;
        uint4 ua = *reinterpret_cast<const uint4*>(&shA[b][idx]);
        p0 = dot2f(bch2(ua.x), bch2(whp[0][j * 4 + 0]), p0);
        p0 = dot2f(bch2(ua.y), bch2(whp[0][j * 4 + 1]), p0);
        p0 = dot2f(bch2(ua.z), bch2(whp[0][j * 4 + 2]), p0);
        p0 = dot2f(bch2(ua.w), bch2(whp[0][j * 4 + 3]), p0);
        p1 = dot2f(bch2(ua.x), bch2(whp[1][j * 4 + 0]), p1);
        p1 = dot2f(bch2(ua.y), bch2(whp[1][j * 4 + 1]), p1);
        p1 = dot2f(bch2(ua.z), bch2(whp[1][j * 4 + 2]), p1);
        p1 = dot2f(bch2(ua.w), bch2(whp[1][j * 4 + 3]), p1);
        if (L1) {
          uint4 ub = *reinterpret_cast<const uint4*>(&shB[b][idx]);
          q0 = dot2f(bch2(ub.x), bch2(wip[0][j * 4 + 0]), q0);
          q0 = dot2f(bch2(ub.y), bch2(wip[0][j * 4 + 1]), q0);
          q0 = dot2f(bch2(ub.z), bch2(wip[0][j * 4 + 2]), q0);
          q0 = dot2f(bch2(ub.w), bch2(wip[0][j * 4 + 3]), q0);
          q1 = dot2f(bch2(ub.x), bch2(wip[1][j * 4 + 0]), q1);
          q1 = dot2f(bch2(ub.y), bch2(wip[1][j * 4 + 1]), q1);
          q1 = dot2f(bch2(ub.z), bch2(wip[1][j * 4 + 2]), q1);
          q1 = dot2f(bch2(ub.w), bch2(wip[1][j * 4 + 3]), q1);
        }
      }
      p0 = red16_(p0); p1 = red16_(p1);
      if (L1) { q0 = red16_(q0); q1 = red16_(q1); }
      if (ks == b) { gA0 = p0; gA1 = p1; gB0 = q0; gB1 = q1; }
    }
    // ---- tagged gate store (f16 pair + tag) ----
    {
      u64* Gw = Gb + (size_t)(t & 1) * (BB * GW) + (size_t)ks * GW;
      if (!L1) {
        stA8(&Gw[pairIdx], pk2(want, gA0, gA1));
      } else if (pairIdx < 512) {
        stA8(&Gw[pairIdx], pk2(want, gA0 + gB0, gA1 + gB1));
      } else {
        stA8(&Gw[pairIdx], pk2(want, gA0, gA1));              // h_n
        stA8(&Gw[pairIdx + 256], pk2(want, gB0, gB1));        // x_n
      }
    }
    __syncthreads();  // matvec reads of shA done before phase-2 overwrites h

    // ---- phase 2: wave owns batches 4w..4w+3; lane owns 8 cols ----
#pragma unroll 1
    for (int bi = 0; bi < 4; ++bi) {
      const int b = wave * 4 + bi;
      const u64* base = Gb + (size_t)(t & 1) * (BB * GW) + (size_t)b * GW + lane * 4;
      float gr[8], gz[8], hn[8], xg[8];
      for (;;) {
        u32 bad = 0;
        u64 r[4], z[4], n[4], x[4];
#pragma unroll
        for (int m = 0; m < 4; ++m) {
          r[m] = ldA(base + m);
          z[m] = ldA(base + 256 + m);
          n[m] = ldA(base + 512 + m);
          bad |= ((u32)(r[m] >> 32) ^ want) | ((u32)(z[m] >> 32) ^ want) |
                 ((u32)(n[m] >> 32) ^ want);
        }
        if (L1) {
#pragma unroll
          for (int m = 0; m < 4; ++m) {
            x[m] = ldA(base + 768 + m);
            bad |= (u32)(x[m] >> 32) ^ want;
          }
        }
        if (!bad) {
#pragma unroll
          for (int m = 0; m < 4; ++m) {
            gr[2 * m] = f16lo((u32)r[m]); gr[2 * m + 1] = f16hi((u32)r[m]);
            gz[2 * m] = f16lo((u32)z[m]); gz[2 * m + 1] = f16hi((u32)z[m]);
            hn[2 * m] = f16lo((u32)n[m]); hn[2 * m + 1] = f16hi((u32)n[m]);
            if (L1) { xg[2 * m] = f16lo((u32)x[m]); xg[2 * m + 1] = f16hi((u32)x[m]); }
          }
          break;
        }
        __builtin_amdgcn_s_sleep(1);
      }
      if (!L1) {  // add x-gates from X0 (plain cached loads)
        const float* Xb = X0 + ((size_t)b * TT + t) * NG3 + lane * 8;
        float4 a0 = *(const float4*)(Xb),        a1 = *(const float4*)(Xb + 4);
        float4 z0 = *(const float4*)(Xb + 512),  z1 = *(const float4*)(Xb + 516);
        float4 n0 = *(const float4*)(Xb + 1024), n1 = *(const float4*)(Xb + 1028);
        gr[0]+=a0.x; gr[1]+=a0.y; gr[2]+=a0.z; gr[3]+=a0.w;
        gr[4]+=a1.x; gr[5]+=a1.y; gr[6]+=a1.z; gr[7]+=a1.w;
        gz[0]+=z0.x; gz[1]+=z0.y; gz[2]+=z0.z; gz[3]+=z0.w;
        gz[4]+=z1.x; gz[5]+=z1.y; gz[6]+=z1.z; gz[7]+=z1.w;
        xg[0]=n0.x; xg[1]=n0.y; xg[2]=n0.z; xg[3]=n0.w;
        xg[4]=n1.x; xg[5]=n1.y; xg[6]=n1.z; xg[7]=n1.w;
      }
      // LN r
      float s = 0.f, s2 = 0.f;
#pragma unroll
      for (int e = 0; e < 8; ++e) { s += gr[e]; s2 += gr[e] * gr[e]; }
      s = red64_(s); s2 = red64_(s2);
      float m = s * (1.f / 512.f);
      float rs = rsqrtf(s2 * (1.f / 512.f) - m * m + LNEPS);
      float rv[8];
#pragma unroll
      for (int e = 0; e < 8; ++e) rv[e] = sigmoidf_((gr[e] - m) * rs * lw[e] + lb[e]);
      // LN z
      s = 0.f; s2 = 0.f;
#pragma unroll
      for (int e = 0; e < 8; ++e) { s += gz[e]; s2 += gz[e] * gz[e]; }
      s = red64_(s); s2 = red64_(s2);
      m = s * (1.f / 512.f);
      rs = rsqrtf(s2 * (1.f / 512.f) - m * m + LNEPS);
      float zv[8];
#pragma unroll
      for (int e = 0; e < 8; ++e) zv[e] = sigmoidf_((gz[e] - m) * rs * lw[8 + e] + lb[8 + e]);
      // n pre-act + LN
      float np[8];
      s = 0.f; s2 = 0.f;
#pragma unroll
      for (int e = 0; e < 8; ++e) {
        np[e] = xg[e] + rv[e] * hn[e];
        s += np[e]; s2 += np[e] * np[e];
      }
      s = red64_(s); s2 = red64_(s2);
      m = s * (1.f / 512.f);
      rs = rsqrtf(s2 * (1.f / 512.f) - m * m + LNEPS);
      // h update
      const int hidx = physp(lane) * 8;
      uint4 ho = *reinterpret_cast<const uint4*>(&shA[b][hidx]);
      float hold[8] = {f16lo(ho.x), f16hi(ho.x), f16lo(ho.y), f16hi(ho.y),
                       f16lo(ho.z), f16hi(ho.z), f16lo(ho.w), f16hi(ho.w)};
      float res[8];
      if (L1) {
        uint4 ro = *reinterpret_cast<const uint4*>(&shB[b][hidx]);
        res[0]=f16lo(ro.x); res[1]=f16hi(ro.x); res[2]=f16lo(ro.y); res[3]=f16hi(ro.y);
        res[4]=f16lo(ro.z); res[5]=f16hi(ro.z); res[6]=f16lo(ro.w); res[7]=f16hi(ro.w);
      }
      float hv[8];
#pragma unroll
      for (int e = 0; e < 8; ++e) {
        float n = tanhf_((np[e] - m) * rs * lw[16 + e] + lb[16 + e]);
        hv[e] = (1.f - zv[e]) * n + zv[e] * hold[e];
        if (L1) hv[e] += res[e];
      }
      *reinterpret_cast<uint4*>(&shA[b][hidx]) =
          make_uint4(pkh2(hv[0], hv[1]), pkh2(hv[2], hv[3]),
                     pkh2(hv[4], hv[5]), pkh2(hv[6], hv[7]));
      if (!L1 && wgl == b) {
        // throttle ring slot overwrite on L1 consumption, then publish h0 row
        if (t >= 4) {
          const u32 w2 = (u32)(t - 3);
          for (;;) {
            bool ok = (lane < NWGL) ? (ldA32(&prog[(size_t)lane * FL]) >= w2) : true;
            if (__all(ok)) break;
            __builtin_amdgcn_s_sleep(2);
          }
        }
        u64* Hw = Hb0 + (size_t)(t & 3) * HSLOT + (size_t)b * 256 + lane * 4;
        stA8(&Hw[0], pk2(want, hv[0], hv[1]));
        stA8(&Hw[1], pk2(want, hv[2], hv[3]));
        stA8(&Hw[2], pk2(want, hv[4], hv[5]));
        stA8(&Hw[3], pk2(want, hv[6], hv[7]));
      }
      if (L1 && wgl == b) {
        float* Or = out + ((size_t)b * TT + t) * 512 + lane * 8;
        *reinterpret_cast<float4*>(Or)     = make_float4(hv[0], hv[1], hv[2], hv[3]);
        *reinterpret_cast<float4*>(Or + 4) = make_float4(hv[4], hv[5], hv[6], hv[7]);
      }
    }
    __syncthreads();  // h(t) complete before next matvec
  }
}

// ---------------- launch ----------------
extern "C" void kernel_launch(void* const* d_in, const int* in_sizes, int n_in,
                              void* d_out, int out_size, void* d_ws, size_t ws_size,
                              hipStream_t stream) {
  (void)in_sizes; (void)n_in; (void)out_size; (void)ws_size;
  const float* x   = (const float*)d_in[0];
  const float* Wi  = (const float*)d_in[1];  // [2][1536][512]
  const float* Wh  = (const float*)d_in[2];  // [2][1536][512]
  const float* lnw = (const float*)d_in[3];  // [2][3][512]
  const float* lnb = (const float*)d_in[4];
  float* out = (float*)d_out;

  float* X0 = (float*)d_ws;                   // [24000][1536] f32
  u64* G0  = (u64*)(X0 + (size_t)GM * NG3);   // [2][16][768]
  u64* G1  = G0 + 2 * BB * GW0;               // [2][16][1024]
  u64* Hb0 = G1 + 2 * BB * GW1;               // [4][16][256]
  u32* prog = (u32*)(Hb0 + 4 * HSLOT);        // [48][64]

  size_t clear_bytes = (size_t)(2 * BB * GW0 + 2 * BB * GW1 + 4 * HSLOT) * 8 +
                       (size_t)NWGL * FL * 4;
  hipMemsetAsync(G0, 0, clear_bytes, stream);

  dim3 ggrid(GM / 64, NG3 / 64);
  gemm_nt<<<ggrid, 256, 0, stream>>>(x, Wi, X0);  // layer-0 input gates
  gru_fused<<<2 * NWGL, 256, 0, stream>>>(
      Wh, Wi + (size_t)NG3 * 512, Wh + (size_t)NG3 * 512, X0, lnw, lnb, out,
      G0, G1, Hb0, prog);
}

// Round 10
// 17283.168 us; speedup vs baseline: 2.1207x; 2.1207x over previous
//
#include <hip/hip_runtime.h>

typedef unsigned long long u64;
typedef unsigned int u32;
typedef unsigned short u16;
typedef _Float16 f16;
typedef _Float16 h2v __attribute__((ext_vector_type(2)));

#define BB 16
#define TT 1500
#define NG3 1536
#define GM (BB * TT)   /* 24000 */
#define GK 512
#define LNEPS 1e-5f
#define NWG 48         /* WGs per role */
#define FL 64          /* flag line stride in u32 (256B) */
#define H0D 8          /* Hb0 ring depth */
#define H1D 4          /* Hb1 ring depth */
#define HROWU 256      /* u32 per h row (512 f16) */
#define GROW 768       /* u32 per gate row (1536 f16) */

// ---------------- helpers ----------------
__device__ __forceinline__ float sigmoidf_(float x) { return 1.f / (1.f + __expf(-x)); }
__device__ __forceinline__ float tanhf_(float x) {
  x = fminf(15.f, fmaxf(-15.f, x));
  float e = __expf(2.f * x);
  return (e - 1.f) / (e + 1.f);
}
__device__ __forceinline__ float red16_(float v) {
  v += __shfl_xor(v, 1, 64); v += __shfl_xor(v, 2, 64);
  v += __shfl_xor(v, 4, 64); v += __shfl_xor(v, 8, 64);
  return v;
}
__device__ __forceinline__ float red64_(float v) {
  v = red16_(v);
  v += __shfl_xor(v, 16, 64); v += __shfl_xor(v, 32, 64);
  return v;
}
__device__ __forceinline__ u32 pkh2(float a, float b) {
  u16 sa = __builtin_bit_cast(u16, (f16)a);
  u16 sb = __builtin_bit_cast(u16, (f16)b);
  return (u32)sa | ((u32)sb << 16);
}
__device__ __forceinline__ float f16lo(u32 p) { u16 s = (u16)p; return (float)__builtin_bit_cast(f16, s); }
__device__ __forceinline__ float f16hi(u32 p) { u16 s = (u16)(p >> 16); return (float)__builtin_bit_cast(f16, s); }
__device__ __forceinline__ h2v bch2(u32 u) { return __builtin_bit_cast(h2v, u); }
__device__ __forceinline__ float dot2f(h2v a, h2v b, float c) {
#if __has_builtin(__builtin_amdgcn_fdot2)
  return __builtin_amdgcn_fdot2(a, b, c, false);
#else
  return fmaf((float)a.y, (float)b.y, fmaf((float)a.x, (float)b.x, c));
#endif
}
// 16B-chunk swizzle within a 64-chunk h row (2-way max on matvec reads)
__device__ __forceinline__ int physp(int c) { return c ^ ((c >> 2) & 7); }

__device__ __forceinline__ u64 ldA(const u64* p) {
  return __hip_atomic_load(p, __ATOMIC_RELAXED, __HIP_MEMORY_SCOPE_AGENT);
}
__device__ __forceinline__ u32 ldA32(const u32* p) {
  return __hip_atomic_load(p, __ATOMIC_RELAXED, __HIP_MEMORY_SCOPE_AGENT);
}
__device__ __forceinline__ void stA32(u32* p, u32 v) {
  __hip_atomic_store(p, v, __ATOMIC_RELAXED, __HIP_MEMORY_SCOPE_AGENT);
}

// ---------------- big GEMM: C[M,N] = A[M,K] @ W[N,K]^T (fp32) ----------------
__global__ __launch_bounds__(256) void gemm_nt(const float* __restrict__ A,
                                               const float* __restrict__ W,
                                               float* __restrict__ C) {
  __shared__ __align__(16) float As[32][68];
  __shared__ __align__(16) float Ws[32][68];
  const int m0 = blockIdx.x * 64;
  const int n0 = blockIdx.y * 64;
  const int tid = threadIdx.x;
  const int tm = tid & 15, tn = tid >> 4;
  float acc[4][4] = {};
  for (int k0 = 0; k0 < GK; k0 += 32) {
#pragma unroll
    for (int u = 0; u < 2; ++u) {
      int idx = tid + u * 256;
      int r = idx >> 3;
      int kq = (idx & 7) * 4;
      float4 a = *reinterpret_cast<const float4*>(&A[(size_t)(m0 + r) * GK + k0 + kq]);
      As[kq + 0][r] = a.x; As[kq + 1][r] = a.y; As[kq + 2][r] = a.z; As[kq + 3][r] = a.w;
      float4 w = *reinterpret_cast<const float4*>(&W[(size_t)(n0 + r) * GK + k0 + kq]);
      Ws[kq + 0][r] = w.x; Ws[kq + 1][r] = w.y; Ws[kq + 2][r] = w.z; Ws[kq + 3][r] = w.w;
    }
    __syncthreads();
#pragma unroll
    for (int kk = 0; kk < 32; ++kk) {
      float a[4], w[4];
      *reinterpret_cast<float4*>(a) = *reinterpret_cast<const float4*>(&As[kk][tm * 4]);
      *reinterpret_cast<float4*>(w) = *reinterpret_cast<const float4*>(&Ws[kk][tn * 4]);
#pragma unroll
      for (int i = 0; i < 4; ++i)
#pragma unroll
        for (int q = 0; q < 4; ++q)
          acc[i][q] = fmaf(a[i], w[q], acc[i][q]);
    }
    __syncthreads();
  }
#pragma unroll
  for (int i = 0; i < 4; ++i) {
    float4 v = make_float4(acc[i][0], acc[i][1], acc[i][2], acc[i][3]);
    *reinterpret_cast<float4*>(&C[(size_t)(m0 + tm * 4 + i) * NG3 + n0 + tn * 4]) = v;
  }
}

// ---------------- fused 2-layer GRU: owner-LN + h-broadcast, flags only ------
// role 0 (WG 0..47):   L0 matvec Wh0·h0; owners (wgl<16) do L0 LN + publish h0
// role 1 (WG 48..95):  L1 matvec Wh1·h1; owners do L1 LN (+resid) + publish h1 + out
// role 2 (WG 96..143): L1 matvec Wi1·h0(t) -> x-gates (one stage early)
// Data untagged (u32 = 2×f16); readiness via flags stored after vmcnt(0) drain.
__global__ __launch_bounds__(256, 1) void gru_fused(
    const float* __restrict__ Wh0, const float* __restrict__ Wi1,
    const float* __restrict__ Wh1, const float* __restrict__ X0,
    const float* __restrict__ lnw, const float* __restrict__ lnb,
    float* __restrict__ out, u32* __restrict__ G0, u32* __restrict__ G1h,
    u32* __restrict__ G1x, u32* __restrict__ Hb0, u32* __restrict__ Hb1,
    u32* __restrict__ flags) {
  u32* flag0  = flags;                 // [48] gate flags L0
  u32* flag1h = flags + 48 * FL;       // [48] gate flags L1h
  u32* flag1x = flags + 96 * FL;       // [48] gate flags L1x
  u32* h0f    = flags + 144 * FL;      // [16] h0 row flags
  u32* h1f    = flags + 160 * FL;      // [16] h1 row flags

  __shared__ __align__(16) u16 shA[BB][544];  // h copy (f16, swizzled chunks)
  __shared__ __align__(16) float red4[4][4];  // owner LN cross-wave combine

  const int tid = threadIdx.x, wg = blockIdx.x;
  const int lane = tid & 63, wave = tid >> 6;
  const int ks = lane & 15, cq = lane >> 4;
  const int role = wg / NWG;            // 0=L0, 1=L1h, 2=L1x
  const int wgl = wg - role * NWG;
  const int pairIdx = wgl * 16 + wave * 4 + cq;  // col-pair 0..767
  const int col0 = pairIdx * 2;
  const int rr = tid >> 4, q16 = tid & 15;       // h-copy assignment

  // ---- persistent weights: this role's matrix, 2 cols, f16-packed ----
  const float* Wsel = (role == 0) ? Wh0 : (role == 1) ? Wh1 : Wi1;
  u32 wp[2][16];
#pragma unroll
  for (int c = 0; c < 2; ++c) {
    const float* Wp = Wsel + (size_t)(col0 + c) * 512 + ks * 32;
#pragma unroll
    for (int i = 0; i < 16; ++i) wp[c][i] = pkh2(Wp[2 * i], Wp[2 * i + 1]);
  }
  // ---- owner setup ----
  const bool own = (role <= 1) && (wgl < 16);
  const int b_own = wgl;
  const float* lnwL = lnw + (role == 1 ? NG3 : 0);
  const float* lnbL = lnb + (role == 1 ? NG3 : 0);
  float lwv[6], lbv[6];
  if (own) {
#pragma unroll
    for (int g = 0; g < 3; ++g)
#pragma unroll
      for (int c = 0; c < 2; ++c) {
        lwv[g * 2 + c] = lnwL[g * 512 + 2 * tid + c];
        lbv[g * 2 + c] = lnbL[g * 512 + 2 * tid + c];
      }
  }
  u32* Gst = (role == 0) ? G0 : (role == 1) ? G1h : G1x;
  u32* myflag = (role == 0) ? flag0 : (role == 1) ? flag1h : flag1x;

  for (int idx = tid; idx < BB * 544; idx += 256) (&shA[0][0])[idx] = 0;
  __syncthreads();

  for (int t = 0; t < TT; ++t) {
    const u32 want = (u32)(t + 1);

    // ---- A: refresh h copy in LDS ----
    if (role == 2) {
      if (tid < 16)
        while (ldA32(&h0f[(size_t)tid * FL]) < want) __builtin_amdgcn_s_sleep(1);
      __syncthreads();
      const u32* Hsrc = Hb0 + (size_t)(t & (H0D - 1)) * (BB * HROWU);
      const u64* src = (const u64*)(Hsrc + (size_t)rr * HROWU) + q16 * 8;
      u32 pl[16];
#pragma unroll
      for (int m = 0; m < 8; ++m) {
        u64 w = ldA(src + m);
        pl[2 * m] = (u32)w; pl[2 * m + 1] = (u32)(w >> 32);
      }
#pragma unroll
      for (int w = 0; w < 4; ++w)
        *reinterpret_cast<uint4*>(&shA[rr][physp(q16 * 4 + w) * 8]) =
            make_uint4(pl[4 * w], pl[4 * w + 1], pl[4 * w + 2], pl[4 * w + 3]);
      __syncthreads();
    } else if (t > 0) {
      u32* hf = (role == 0) ? h0f : h1f;
      if (tid < 16)
        while (ldA32(&hf[(size_t)tid * FL]) < (u32)t) __builtin_amdgcn_s_sleep(1);
      __syncthreads();
      const u32* Hsrc = (role == 0)
          ? Hb0 + (size_t)((t - 1) & (H0D - 1)) * (BB * HROWU)
          : Hb1 + (size_t)((t - 1) & (H1D - 1)) * (BB * HROWU);
      const u64* src = (const u64*)(Hsrc + (size_t)rr * HROWU) + q16 * 8;
      u32 pl[16];
#pragma unroll
      for (int m = 0; m < 8; ++m) {
        u64 w = ldA(src + m);
        pl[2 * m] = (u32)w; pl[2 * m + 1] = (u32)(w >> 32);
      }
#pragma unroll
      for (int w = 0; w < 4; ++w)
        *reinterpret_cast<uint4*>(&shA[rr][physp(q16 * 4 + w) * 8]) =
            make_uint4(pl[4 * w], pl[4 * w + 1], pl[4 * w + 2], pl[4 * w + 3]);
      __syncthreads();
    }

    // ---- B: matvec (thread = (ks, col-pair); reduce over 16 lanes) ----
    float g0 = 0.f, g1 = 0.f;
#pragma unroll 4
    for (int b = 0; b < 16; ++b) {
      float p0 = 0.f, p1 = 0.f;
#pragma unroll
      for (int j = 0; j < 4; ++j) {
        const int idx = ((ks * 4 + j) ^ (ks & 7)) * 8;
        uint4 ua = *reinterpret_cast<const uint4*>(&shA[b][idx]);
        p0 = dot2f(bch2(ua.x), bch2(wp[0][j * 4 + 0]), p0);
        p0 = dot2f(bch2(ua.y), bch2(wp[0][j * 4 + 1]), p0);
        p0 = dot2f(bch2(ua.z), bch2(wp[0][j * 4 + 2]), p0);
        p0 = dot2f(bch2(ua.w), bch2(wp[0][j * 4 + 3]), p0);
        p1 = dot2f(bch2(ua.x), bch2(wp[1][j * 4 + 0]), p1);
        p1 = dot2f(bch2(ua.y), bch2(wp[1][j * 4 + 1]), p1);
        p1 = dot2f(bch2(ua.z), bch2(wp[1][j * 4 + 2]), p1);
        p1 = dot2f(bch2(ua.w), bch2(wp[1][j * 4 + 3]), p1);
      }
      p0 = red16_(p0); p1 = red16_(p1);
      if (ks == b) { g0 = p0; g1 = p1; }
    }
    // G1x overwrite gate: L1h owners must have consumed G1x(t-2)
    if (role == 2 && t >= 2) {
      const u32 w2 = (u32)(t - 1);
      while (ldA32(&h1f[(size_t)(tid & 15) * FL]) < w2) __builtin_amdgcn_s_sleep(1);
    }
    stA32(&Gst[(size_t)(t & 1) * (BB * GROW) + (size_t)ks * GROW + pairIdx], pkh2(g0, g1));
    asm volatile("s_waitcnt vmcnt(0)" ::: "memory");
    __syncthreads();
    if (tid == 0) stA32(&myflag[(size_t)wgl * FL], want);

    // ---- C: owner phase (LN + h update + publish) ----
    if (own) {
      if (role == 0) {
        if (lane < 48)
          while (ldA32(&flag0[(size_t)lane * FL]) < want) __builtin_amdgcn_s_sleep(1);
      } else {
        if (lane < 48) {
          while (ldA32(&flag1h[(size_t)lane * FL]) < want) __builtin_amdgcn_s_sleep(1);
          while (ldA32(&flag1x[(size_t)lane * FL]) < want) __builtin_amdgcn_s_sleep(1);
        }
      }
      const size_t gbase = (size_t)(t & 1) * (BB * GROW) + (size_t)b_own * GROW + tid;
      float gr0, gr1, gz0, gz1, hn0, hn1, xn0, xn1;
      {
        const u32* Gr = (role == 0) ? G0 : G1h;
        u32 pr = ldA32(&Gr[gbase]);
        u32 pz = ldA32(&Gr[gbase + 256]);
        u32 pn = ldA32(&Gr[gbase + 512]);
        gr0 = f16lo(pr); gr1 = f16hi(pr);
        gz0 = f16lo(pz); gz1 = f16hi(pz);
        hn0 = f16lo(pn); hn1 = f16hi(pn);
      }
      if (role == 1) {
        u32 qr = ldA32(&G1x[gbase]);
        u32 qz = ldA32(&G1x[gbase + 256]);
        u32 qx = ldA32(&G1x[gbase + 512]);
        gr0 += f16lo(qr); gr1 += f16hi(qr);
        gz0 += f16lo(qz); gz1 += f16hi(qz);
        xn0 = f16lo(qx); xn1 = f16hi(qx);
      } else {
        const float* Xr = X0 + ((size_t)b_own * TT + t) * NG3 + 2 * tid;
        float2 xr = *reinterpret_cast<const float2*>(Xr);
        float2 xz = *reinterpret_cast<const float2*>(Xr + 512);
        float2 xl = *reinterpret_cast<const float2*>(Xr + 1024);
        gr0 += xr.x; gr1 += xr.y;
        gz0 += xz.x; gz1 += xz.y;
        xn0 = xl.x; xn1 = xl.y;
      }
      // LN r & z (one cross-wave combine)
      float sr = red64_(gr0 + gr1), sr2 = red64_(gr0 * gr0 + gr1 * gr1);
      float sz = red64_(gz0 + gz1), sz2 = red64_(gz0 * gz0 + gz1 * gz1);
      if (lane == 0) {
        red4[wave][0] = sr; red4[wave][1] = sr2;
        red4[wave][2] = sz; red4[wave][3] = sz2;
      }
      __syncthreads();
      float tsr = 0, tsr2 = 0, tsz = 0, tsz2 = 0;
#pragma unroll
      for (int w = 0; w < 4; ++w) {
        tsr += red4[w][0]; tsr2 += red4[w][1];
        tsz += red4[w][2]; tsz2 += red4[w][3];
      }
      const float mr = tsr * (1.f / 512.f);
      const float rsr = rsqrtf(tsr2 * (1.f / 512.f) - mr * mr + LNEPS);
      const float mz = tsz * (1.f / 512.f);
      const float rsz = rsqrtf(tsz2 * (1.f / 512.f) - mz * mz + LNEPS);
      const float rv0 = sigmoidf_((gr0 - mr) * rsr * lwv[0] + lbv[0]);
      const float rv1 = sigmoidf_((gr1 - mr) * rsr * lwv[1] + lbv[1]);
      const float zv0 = sigmoidf_((gz0 - mz) * rsz * lwv[2] + lbv[2]);
      const float zv1 = sigmoidf_((gz1 - mz) * rsz * lwv[3] + lbv[3]);
      // LN n
      const float np0 = xn0 + rv0 * hn0;
      const float np1 = xn1 + rv1 * hn1;
      float sn = red64_(np0 + np1), sn2 = red64_(np0 * np0 + np1 * np1);
      __syncthreads();  // red4 reads done before overwrite
      if (lane == 0) { red4[wave][0] = sn; red4[wave][1] = sn2; }
      __syncthreads();
      float tn = red4[0][0] + red4[1][0] + red4[2][0] + red4[3][0];
      float tn2 = red4[0][1] + red4[1][1] + red4[2][1] + red4[3][1];
      const float mn = tn * (1.f / 512.f);
      const float rsn = rsqrtf(tn2 * (1.f / 512.f) - mn * mn + LNEPS);
      // h update (hold from local LDS copy)
      u32 hp = *reinterpret_cast<const u32*>(&shA[b_own][physp(tid >> 2) * 8 + 2 * (tid & 3)]);
      const float n0 = tanhf_((np0 - mn) * rsn * lwv[4] + lbv[4]);
      const float n1 = tanhf_((np1 - mn) * rsn * lwv[5] + lbv[5]);
      float hv0 = (1.f - zv0) * n0 + zv0 * f16lo(hp);
      float hv1 = (1.f - zv1) * n1 + zv1 * f16hi(hp);
      if (role == 1) {  // residual h0(t) + final output
        while (ldA32(&h0f[(size_t)b_own * FL]) < want) __builtin_amdgcn_s_sleep(1);
        u32 r0 = ldA32(&Hb0[(size_t)(t & (H0D - 1)) * (BB * HROWU) + (size_t)b_own * HROWU + tid]);
        hv0 += f16lo(r0); hv1 += f16hi(r0);
        *reinterpret_cast<float2*>(&out[((size_t)b_own * TT + t) * 512 + 2 * tid]) =
            make_float2(hv0, hv1);
      }
      // ring-overwrite throttles (reference strictly older steps)
      if (role == 0 && t >= H0D) {
        const u32 w2 = (u32)(t - (H0D - 1));
        if (lane < 48)
          while (ldA32(&flag1x[(size_t)lane * FL]) < w2) __builtin_amdgcn_s_sleep(1);
        if (lane < 16)
          while (ldA32(&h1f[(size_t)lane * FL]) < w2) __builtin_amdgcn_s_sleep(1);
      }
      if (role == 1 && t >= H1D) {
        const u32 w2 = (u32)(t - 2);
        if (lane < 48)
          while (ldA32(&flag1h[(size_t)lane * FL]) < w2) __builtin_amdgcn_s_sleep(1);
      }
      // publish h row + flag
      u32* Hw = (role == 0)
          ? Hb0 + (size_t)(t & (H0D - 1)) * (BB * HROWU) + (size_t)b_own * HROWU
          : Hb1 + (size_t)(t & (H1D - 1)) * (BB * HROWU) + (size_t)b_own * HROWU;
      stA32(&Hw[tid], pkh2(hv0, hv1));
      asm volatile("s_waitcnt vmcnt(0)" ::: "memory");
      __syncthreads();
      if (tid == 0) stA32(&((role == 0) ? h0f : h1f)[(size_t)b_own * FL], want);
    }
  }
}

// ---------------- launch ----------------
extern "C" void kernel_launch(void* const* d_in, const int* in_sizes, int n_in,
                              void* d_out, int out_size, void* d_ws, size_t ws_size,
                              hipStream_t stream) {
  (void)in_sizes; (void)n_in; (void)out_size; (void)ws_size;
  const float* x   = (const float*)d_in[0];
  const float* Wi  = (const float*)d_in[1];  // [2][1536][512]
  const float* Wh  = (const float*)d_in[2];  // [2][1536][512]
  const float* lnw = (const float*)d_in[3];  // [2][3][512]
  const float* lnb = (const float*)d_in[4];
  float* out = (float*)d_out;

  float* X0 = (float*)d_ws;                     // [24000][1536] f32
  u32* G0   = (u32*)(X0 + (size_t)GM * NG3);    // [2][16][768]
  u32* G1h  = G0 + 2 * BB * GROW;               // [2][16][768]
  u32* G1x  = G1h + 2 * BB * GROW;              // [2][16][768]
  u32* Hb0  = G1x + 2 * BB * GROW;              // [8][16][256]
  u32* Hb1  = Hb0 + H0D * BB * HROWU;           // [4][16][256]
  u32* flags = Hb1 + H1D * BB * HROWU;          // 176 flag lines

  size_t clear_bytes = (size_t)(3 * 2 * BB * GROW + H0D * BB * HROWU +
                                H1D * BB * HROWU + 176 * FL) * 4;
  hipMemsetAsync(G0, 0, clear_bytes, stream);

  dim3 ggrid(GM / 64, NG3 / 64);
  gemm_nt<<<ggrid, 256, 0, stream>>>(x, Wi, X0);  // layer-0 input gates
  gru_fused<<<3 * NWG, 256, 0, stream>>>(
      Wh, Wi + (size_t)NG3 * 512, Wh + (size_t)NG3 * 512, X0, lnw, lnb, out,
      G0, G1h, G1x, Hb0, Hb1, flags);
}